// Round 5
// baseline (3878.659 us; speedup 1.0000x reference)
//
#include <hip/hip_runtime.h>
#include <cstddef>

// ---------------------------------------------------------------------------
// RNNModel round 5: persistent-kernel recurrence (1 launch/layer, software
// grid barrier between timesteps) + pure-bf16 hi|lo K=2048 MFMA GEMMs.
// Gate perm: out col n <-> W row perm_g(n)=((n>>4)&3)*1024+(n>>6)*16+(n&15)
// Chunk perm: within each 128B row-segment, 16B chunk c stored at c^(row&7).
// ---------------------------------------------------------------------------

static constexpr int T_ = 50, B_ = 64, E_ = 1024, H_ = 1024, V_ = 32000;
static constexpr int G_ = 4096;

typedef unsigned short u16;
typedef __attribute__((ext_vector_type(8))) short bf16x8;
typedef __attribute__((ext_vector_type(8))) unsigned short u16x8;
typedef __attribute__((ext_vector_type(4))) float f32x4;

__device__ __forceinline__ int perm_g(int n) {
  return ((n >> 4) & 3) * H_ + (n >> 6) * 16 + (n & 15);
}
__device__ __forceinline__ u16 bf16_rn(float x) {
  union { float f; unsigned u; } a; a.f = x;
  unsigned r = a.u + 0x7fffu + ((a.u >> 16) & 1u);
  return (u16)(r >> 16);
}
__device__ __forceinline__ float bf16_f(u16 h) {
  union { float f; unsigned u; } a; a.u = ((unsigned)h) << 16;
  return a.f;
}
__device__ __forceinline__ float sigm(float x) { return 1.f / (1.f + __expf(-x)); }

__global__ void fill_zero(float* p, int n) {
  int i = blockIdx.x * blockDim.x + threadIdx.x;
  if (i < n) p[i] = 0.f;
}
__global__ void bias_perm(const float* a, const float* b, float* dst) {
  int n = blockIdx.x * 256 + threadIdx.x;
  int s = perm_g(n);
  dst[n] = a[s] + b[s];
}

// f32 -> bf16 hi|lo [rows x 2048] with chunk permute.
__global__ void conv_w(const float* __restrict__ src, int srcld, int coloff,
                       const int* __restrict__ gidx, int PERM, int rows,
                       u16* __restrict__ dst) {
  int idx = blockIdx.x * 256 + threadIdx.x;
  int r = idx >> 7, kc = (idx & 127) << 3;
  if (r >= rows) return;
  int s = gidx ? gidx[r] : (PERM ? perm_g(r) : r);
  const float* p = src + (size_t)s * srcld + coloff + kc;
  float4 v0 = *(const float4*)p, v1 = *(const float4*)(p + 4);
  float vv[8] = {v0.x, v0.y, v0.z, v0.w, v1.x, v1.y, v1.z, v1.w};
  u16x8 hi, lo;
#pragma unroll
  for (int i = 0; i < 8; ++i) {
    u16 h = bf16_rn(vv[i]);
    hi[i] = h;
    lo[i] = bf16_rn(vv[i] - bf16_f(h));
  }
  size_t o = (size_t)r * 2048 + ((kc >> 6) << 6) + ((((kc >> 3) & 7) ^ (r & 7)) << 3);
  *(u16x8*)&dst[o] = hi;
  *(u16x8*)&dst[o + 1024] = lo;
}

// ------------------------- fp32 tiled GEMM (c0 init) ------------------------
template<int BM, int BN, int BK, int TM, int TN>
__launch_bounds__(256)
__global__ void gemm_nt(
    const float* __restrict__ A, const int* __restrict__ Aidx, int lda,
    const float* __restrict__ W, int ldw, int koff,
    const float* __restrict__ bias,
    const float* __restrict__ Dadd, int ldd, int dmask,
    float* __restrict__ C, int ldc, int M, int N, int K) {
  constexpr int TX = BN / TN;
  constexpr int TY = BM / TM;
  static_assert(TX * TY == 256, "thread geometry");
  __shared__ float As[BK][BM + 4];
  __shared__ float Ws[BK][BN + 4];
  const int tid = threadIdx.x;
  const int tx = tid % TX, ty = tid / TX;
  const int m0 = blockIdx.y * BM, n0 = blockIdx.x * BN;
  float acc[TM][TN];
#pragma unroll
  for (int i = 0; i < TM; ++i)
#pragma unroll
    for (int j = 0; j < TN; ++j) acc[i][j] = 0.f;
  constexpr int AV = (BM * BK) / 4;
  constexpr int WV = (BN * BK) / 4;
  constexpr int KV = BK / 4;
  for (int k0 = 0; k0 < K; k0 += BK) {
#pragma unroll
    for (int lp = 0; lp < (AV + 255) / 256; ++lp) {
      int e = tid + lp * 256;
      if (e < AV) {
        int r = e / KV, kq = e % KV;
        int m = m0 + r;
        float4 v = make_float4(0.f, 0.f, 0.f, 0.f);
        if (m < M) {
          int row = Aidx ? Aidx[m] : m;
          v = *(const float4*)&A[(size_t)row * lda + k0 + kq * 4];
        }
        As[kq * 4 + 0][r] = v.x; As[kq * 4 + 1][r] = v.y;
        As[kq * 4 + 2][r] = v.z; As[kq * 4 + 3][r] = v.w;
      }
    }
#pragma unroll
    for (int lp = 0; lp < (WV + 255) / 256; ++lp) {
      int e = tid + lp * 256;
      if (e < WV) {
        int cc = e / KV, kq = e % KV;
        int n = n0 + cc;
        float4 v = make_float4(0.f, 0.f, 0.f, 0.f);
        if (n < N)
          v = *(const float4*)&W[(size_t)n * ldw + koff + k0 + kq * 4];
        Ws[kq * 4 + 0][cc] = v.x; Ws[kq * 4 + 1][cc] = v.y;
        Ws[kq * 4 + 2][cc] = v.z; Ws[kq * 4 + 3][cc] = v.w;
      }
    }
    __syncthreads();
#pragma unroll
    for (int kk = 0; kk < BK; ++kk) {
      float a[TM], b[TN];
#pragma unroll
      for (int i = 0; i < TM; ++i) a[i] = As[kk][ty * TM + i];
#pragma unroll
      for (int j = 0; j < TN; ++j) b[j] = Ws[kk][tx * TN + j];
#pragma unroll
      for (int i = 0; i < TM; ++i)
#pragma unroll
        for (int j = 0; j < TN; ++j)
          acc[i][j] += a[i] * b[j];
    }
    __syncthreads();
  }
#pragma unroll
  for (int i = 0; i < TM; ++i) {
    int m = m0 + ty * TM + i;
    if (m >= M) continue;
#pragma unroll
    for (int j = 0; j < TN; ++j) {
      int n = n0 + tx * TN + j;
      if (n >= N) continue;
      float v = acc[i][j];
      if (bias) v += bias[n];
      if (Dadd) {
        int dr = (dmask < 0) ? m : (m & dmask);
        v += Dadd[(size_t)dr * ldd + n];
      }
      C[(size_t)m * ldc + n] = v;
    }
  }
}

// ----------------- pure-bf16 MFMA GEMM: C = A @ Wb^T (+bias)(+Dadd) --------
__launch_bounds__(256)
__global__ void gemm_bt(const u16* __restrict__ A, int Mrows,
                        const u16* __restrict__ Wb,
                        const float* __restrict__ bias,
                        const float* __restrict__ Dadd, int ldd, int dmask,
                        float* __restrict__ C, int ldc, int N, int nbx) {
  __shared__ u16 lsA[128 * 64];
  __shared__ u16 lsB[128 * 64];

  int nwg = gridDim.x, bid = blockIdx.x;
  int q = nwg >> 3, r = nwg & 7;
  int xcd = bid & 7, base = bid >> 3;
  int wg = (xcd < r ? xcd * (q + 1) : r * (q + 1) + (xcd - r) * q) + base;
  int bx = wg % nbx, by = wg / nbx;
  const int m0 = by * 128, n0 = bx * 128;

  const int tid = threadIdx.x, w = tid >> 6, l = tid & 63;
  const int lr = l & 15, lq = l >> 4;
  const int wm = (w >> 1) * 64, wn = (w & 1) * 64;

  f32x4 acc[4][4] = {};

  for (int kt = 0; kt < 32; ++kt) {
#pragma unroll
    for (int i = 0; i < 4; ++i) {
      int rb = w * 32 + i * 8;
      int gm = m0 + rb + (l >> 3);
      if (gm > Mrows - 1) gm = Mrows - 1;
      const u16* ga = A + (size_t)gm * 2048 + kt * 64 + (l & 7) * 8;
      __builtin_amdgcn_global_load_lds(
          (const __attribute__((address_space(1))) void*)ga,
          (__attribute__((address_space(3))) void*)(lsA + rb * 64), 16, 0, 0);
      const u16* gb = Wb + (size_t)(n0 + rb + (l >> 3)) * 2048 + kt * 64 + (l & 7) * 8;
      __builtin_amdgcn_global_load_lds(
          (const __attribute__((address_space(1))) void*)gb,
          (__attribute__((address_space(3))) void*)(lsB + rb * 64), 16, 0, 0);
    }
    asm volatile("s_waitcnt vmcnt(0)" ::: "memory");
    __syncthreads();

    bf16x8 af[4][2], bfr[4][2];
#pragma unroll
    for (int i = 0; i < 4; ++i) {
      int ar = wm + i * 16 + lr;
#pragma unroll
      for (int s = 0; s < 2; ++s)
        af[i][s] = *(const bf16x8*)&lsA[ar * 64 + (((s << 2) + lq) ^ (ar & 7)) * 8];
    }
#pragma unroll
    for (int j = 0; j < 4; ++j) {
      int br = wn + j * 16 + lr;
#pragma unroll
      for (int s = 0; s < 2; ++s)
        bfr[j][s] = *(const bf16x8*)&lsB[br * 64 + (((s << 2) + lq) ^ (br & 7)) * 8];
    }
#pragma unroll
    for (int i = 0; i < 4; ++i)
#pragma unroll
      for (int j = 0; j < 4; ++j) {
        acc[i][j] = __builtin_amdgcn_mfma_f32_16x16x32_bf16(af[i][0], bfr[j][0], acc[i][j], 0, 0, 0);
        acc[i][j] = __builtin_amdgcn_mfma_f32_16x16x32_bf16(af[i][1], bfr[j][1], acc[i][j], 0, 0, 0);
      }
    __syncthreads();
  }

#pragma unroll
  for (int i = 0; i < 4; ++i) {
    int mbase = m0 + wm + i * 16 + lq * 4;
#pragma unroll
    for (int j = 0; j < 4; ++j) {
      int n = n0 + wn + j * 16 + lr;
      float badd = bias ? bias[n] : 0.f;
#pragma unroll
      for (int rr = 0; rr < 4; ++rr) {
        int m = mbase + rr;
        if (m >= Mrows) continue;
        float v = acc[i][j][rr] + badd;
        if (Dadd) {
          int dr = (dmask < 0) ? m : (m & dmask);
          v += Dadd[(size_t)dr * ldd + n];
        }
        C[(size_t)m * ldc + n] = v;
      }
    }
  }
}

// ----------- split-bf16 MFMA GEMM on f32 inputs (tier2/tiny decoder) -------
template<bool GATHER, bool WPERM>
__launch_bounds__(256)
__global__ void gemm_sp(
    const float* __restrict__ A, const int* __restrict__ Aidx, int lda,
    const float* __restrict__ W, int ldw, int koff,
    const float* __restrict__ bias,
    const float* __restrict__ Dadd, int ldd, int dmask,
    float* __restrict__ C, int ldc, int M, int N, int K, int nbx) {
  __shared__ u16 As_h[128][40], As_l[128][40];
  __shared__ u16 Ws_h[128][40], Ws_l[128][40];
  int nwg = gridDim.x, bid = blockIdx.x;
  int q = nwg >> 3, r = nwg & 7;
  int xcd = bid & 7, base = bid >> 3;
  int wg = (xcd < r ? xcd * (q + 1) : r * (q + 1) + (xcd - r) * q) + base;
  int bx = wg % nbx, by = wg / nbx;
  const int m0 = by * 128, n0 = bx * 128;
  const int tid = threadIdx.x;
  const int wave = tid >> 6, lane = tid & 63;
  const int lr = lane & 15, lq = lane >> 4;
  const int wm = (wave >> 1) * 64, wn = (wave & 1) * 64;
  f32x4 acc[4][4] = {};
  for (int k0 = 0; k0 < K; k0 += 32) {
#pragma unroll
    for (int lp = 0; lp < 4; ++lp) {
      int s = tid + lp * 256;
      int row = s >> 3, kq = s & 7;
      float4 v = make_float4(0.f, 0.f, 0.f, 0.f);
      int gm = m0 + row;
      if (gm < M) {
        int src = GATHER ? Aidx[gm] : gm;
        v = *(const float4*)&A[(size_t)src * lda + k0 + kq * 4];
      }
      u16 h0 = bf16_rn(v.x), h1 = bf16_rn(v.y), h2 = bf16_rn(v.z), h3 = bf16_rn(v.w);
      u16 l0 = bf16_rn(v.x - bf16_f(h0)), l1 = bf16_rn(v.y - bf16_f(h1));
      u16 l2 = bf16_rn(v.z - bf16_f(h2)), l3 = bf16_rn(v.w - bf16_f(h3));
      *(uint2*)&As_h[row][kq * 4] =
          make_uint2((unsigned)h0 | ((unsigned)h1 << 16), (unsigned)h2 | ((unsigned)h3 << 16));
      *(uint2*)&As_l[row][kq * 4] =
          make_uint2((unsigned)l0 | ((unsigned)l1 << 16), (unsigned)l2 | ((unsigned)l3 << 16));
    }
#pragma unroll
    for (int lp = 0; lp < 4; ++lp) {
      int s = tid + lp * 256;
      int col = s >> 3, kq = s & 7;
      int n = n0 + col;
      float4 v = make_float4(0.f, 0.f, 0.f, 0.f);
      if (n < N) {
        int srow = WPERM ? perm_g(n) : n;
        v = *(const float4*)&W[(size_t)srow * ldw + koff + k0 + kq * 4];
      }
      u16 h0 = bf16_rn(v.x), h1 = bf16_rn(v.y), h2 = bf16_rn(v.z), h3 = bf16_rn(v.w);
      u16 l0 = bf16_rn(v.x - bf16_f(h0)), l1 = bf16_rn(v.y - bf16_f(h1));
      u16 l2 = bf16_rn(v.z - bf16_f(h2)), l3 = bf16_rn(v.w - bf16_f(h3));
      *(uint2*)&Ws_h[col][kq * 4] =
          make_uint2((unsigned)h0 | ((unsigned)h1 << 16), (unsigned)h2 | ((unsigned)h3 << 16));
      *(uint2*)&Ws_l[col][kq * 4] =
          make_uint2((unsigned)l0 | ((unsigned)l1 << 16), (unsigned)l2 | ((unsigned)l3 << 16));
    }
    __syncthreads();
    bf16x8 ah[4], al[4], bh[4], bl[4];
#pragma unroll
    for (int i = 0; i < 4; ++i) {
      ah[i] = *(const bf16x8*)&As_h[wm + i * 16 + lr][lq * 8];
      al[i] = *(const bf16x8*)&As_l[wm + i * 16 + lr][lq * 8];
    }
#pragma unroll
    for (int j = 0; j < 4; ++j) {
      bh[j] = *(const bf16x8*)&Ws_h[wn + j * 16 + lr][lq * 8];
      bl[j] = *(const bf16x8*)&Ws_l[wn + j * 16 + lr][lq * 8];
    }
#pragma unroll
    for (int i = 0; i < 4; ++i)
#pragma unroll
      for (int j = 0; j < 4; ++j) {
        acc[i][j] = __builtin_amdgcn_mfma_f32_16x16x32_bf16(ah[i], bh[j], acc[i][j], 0, 0, 0);
        acc[i][j] = __builtin_amdgcn_mfma_f32_16x16x32_bf16(ah[i], bl[j], acc[i][j], 0, 0, 0);
        acc[i][j] = __builtin_amdgcn_mfma_f32_16x16x32_bf16(al[i], bh[j], acc[i][j], 0, 0, 0);
      }
    __syncthreads();
  }
#pragma unroll
  for (int i = 0; i < 4; ++i) {
    int mbase = m0 + wm + i * 16 + lq * 4;
#pragma unroll
    for (int j = 0; j < 4; ++j) {
      int n = n0 + wn + j * 16 + lr;
      if (n >= N) continue;
      float badd = bias ? bias[WPERM ? perm_g(n) : n] : 0.f;
#pragma unroll
      for (int rr = 0; rr < 4; ++rr) {
        int m = mbase + rr;
        if (m >= M) continue;
        float v = acc[i][j][rr] + badd;
        if (Dadd) {
          int dr = (dmask < 0) ? m : (m & dmask);
          v += Dadd[(size_t)dr * ldd + n];
        }
        C[(size_t)m * ldc + n] = v;
      }
    }
  }
}

// ---------------- persistent recurrence: 1 launch per layer -----------------
// 128 blocks x 128 threads. Block: rows rg*32..+32, perm'd cols ct*64..+64.
// XCD map: x=bid&7 owns ct in [x*8,x*8+8) -> Whh slice (2MB) L2-resident.
// hs: [T+1][64][2048] u16 chunk-permuted slots; slot 0 = zeros.
template<bool EMIT>
__launch_bounds__(128, 1)
__global__ void rnn_pers(const u16* __restrict__ Wb, const float* __restrict__ xgall,
                         float* __restrict__ cL, float* __restrict__ hL,
                         u16* __restrict__ hs, float* __restrict__ hsf,
                         unsigned* __restrict__ bar, int T) {
  __shared__ u16 lsA[2][32 * 128];
  __shared__ u16 lsB[2][64 * 128];

  const int bid = blockIdx.x;
  const int x = bid & 7, i5 = bid >> 3;
  const int ct = x * 8 + (i5 & 7);
  const int rg = i5 >> 3;
  const int n0 = ct * 64;
  const int tid = threadIdx.x, w = tid >> 6, l = tid & 63;
  const int lr = l & 15, lq = l >> 4;

  const u16* WbB = Wb + (size_t)n0 * 2048;

  const int mb = rg * 32 + w * 16 + lq * 4;   // first of this thread's 4 rows
  const int u = ct * 16 + lr;                 // this thread's unit
  float creg[4];
#pragma unroll
  for (int rr = 0; rr < 4; ++rr) creg[rr] = cL[(mb + rr) * H_ + u];

  unsigned sync_no = 0;

  for (int t = 0; t < T; ++t) {
    const u16* hp = hs + (size_t)t * (B_ * 2048);
    const float* xg = xgall + (size_t)t * ((size_t)B_ * G_);

    f32x4 acc[4] = {};

    // prologue: stage chunk 0 -> buf 0
#pragma unroll
    for (int ii = 0; ii < 4; ++ii) {
      const u16* ga = hp + (size_t)(rg * 32 + w * 16 + ii * 4 + (l >> 4)) * 2048 + (l & 15) * 8;
      __builtin_amdgcn_global_load_lds(
          (const __attribute__((address_space(1))) void*)ga,
          (__attribute__((address_space(3))) void*)(&lsA[0][(w * 16 + ii * 4) * 128]), 16, 0, 0);
    }
#pragma unroll
    for (int ii = 0; ii < 8; ++ii) {
      const u16* gb = WbB + (size_t)(w * 32 + ii * 4 + (l >> 4)) * 2048 + (l & 15) * 8;
      __builtin_amdgcn_global_load_lds(
          (const __attribute__((address_space(1))) void*)gb,
          (__attribute__((address_space(3))) void*)(&lsB[0][(w * 32 + ii * 4) * 128]), 16, 0, 0);
    }

#pragma unroll 2
    for (int kc = 0; kc < 16; ++kc) {
      const int cur = kc & 1;
      if (kc < 15) {
        const int kb = (kc + 1) * 128;
#pragma unroll
        for (int ii = 0; ii < 4; ++ii) {
          const u16* ga = hp + (size_t)(rg * 32 + w * 16 + ii * 4 + (l >> 4)) * 2048 + kb + (l & 15) * 8;
          __builtin_amdgcn_global_load_lds(
              (const __attribute__((address_space(1))) void*)ga,
              (__attribute__((address_space(3))) void*)(&lsA[cur ^ 1][(w * 16 + ii * 4) * 128]), 16, 0, 0);
        }
#pragma unroll
        for (int ii = 0; ii < 8; ++ii) {
          const u16* gb = WbB + (size_t)(w * 32 + ii * 4 + (l >> 4)) * 2048 + kb + (l & 15) * 8;
          __builtin_amdgcn_global_load_lds(
              (const __attribute__((address_space(1))) void*)gb,
              (__attribute__((address_space(3))) void*)(&lsB[cur ^ 1][(w * 32 + ii * 4) * 128]), 16, 0, 0);
        }
        asm volatile("s_waitcnt vmcnt(12)" ::: "memory");
      } else {
        asm volatile("s_waitcnt vmcnt(0)" ::: "memory");
      }
      __syncthreads();

      bf16x8 af[4];
      const int ar = w * 16 + lr;
#pragma unroll
      for (int ks = 0; ks < 4; ++ks)
        af[ks] = *(const bf16x8*)&lsA[cur][ar * 128 + (ks >> 1) * 64 + ((((ks & 1) << 2) + lq) ^ (ar & 7)) * 8];
#pragma unroll
      for (int j = 0; j < 4; ++j) {
        const int br = j * 16 + lr;
#pragma unroll
        for (int ks = 0; ks < 4; ++ks) {
          bf16x8 bv = *(const bf16x8*)&lsB[cur][br * 128 + (ks >> 1) * 64 + ((((ks & 1) << 2) + lq) ^ (br & 7)) * 8];
          acc[j] = __builtin_amdgcn_mfma_f32_16x16x32_bf16(af[ks], bv, acc[j], 0, 0, 0);
        }
      }
      __syncthreads();
    }
    __builtin_amdgcn_sched_barrier(0);

    // ---- LSTM cell (thread-local: acc[j][rr] = gate j of (row mb+rr, unit u))
    u16* hnext = hs + (size_t)(t + 1) * (B_ * 2048);
#pragma unroll
    for (int rr = 0; rr < 4; ++rr) {
      const int m = mb + rr;
      const float* xr = xg + (size_t)m * G_ + n0 + lr;
      float gi = acc[0][rr] + xr[0];
      float gf = acc[1][rr] + xr[16];
      float gg = acc[2][rr] + xr[32];
      float go = acc[3][rr] + xr[48];
      float cn = sigm(gf) * creg[rr] + sigm(gi) * tanhf(gg);
      float hn = sigm(go) * tanhf(cn);
      creg[rr] = cn;
      if (EMIT) hsf[(size_t)t * (B_ * H_) + m * H_ + u] = hn;
      if (t == T - 1) { cL[m * H_ + u] = cn; hL[m * H_ + u] = hn; }
      u16 hh = bf16_rn(hn);
      u16 hl2 = bf16_rn(hn - bf16_f(hh));
      size_t oh = (size_t)m * 2048 + ((u >> 6) << 6) + ((((u >> 3) & 7) ^ (m & 7)) << 3) + (u & 7);
      hnext[oh] = hh;
      hnext[oh + 1024] = hl2;
    }

    // ---- software grid barrier (skip after last step)
    if (t < T - 1) {
      __syncthreads();
      __threadfence();
      ++sync_no;
      if (tid == 0) {
        __hip_atomic_fetch_add(bar, 1u, __ATOMIC_RELEASE, __HIP_MEMORY_SCOPE_AGENT);
        while (__hip_atomic_load(bar, __ATOMIC_RELAXED, __HIP_MEMORY_SCOPE_AGENT) <
               128u * sync_no) {}
      }
      __syncthreads();
      __threadfence();
    }
  }
}

// --------- single-step kernel (tiny-ws fallback, from round 4) -------------
template<bool EMIT_F32>
__launch_bounds__(256)
__global__ void rnn_step(const u16* __restrict__ hprev, const u16* __restrict__ Wb,
                         const float* __restrict__ xg,
                         float* __restrict__ c, float* __restrict__ hf,
                         u16* __restrict__ hbf_out, float* __restrict__ hsf) {
  __shared__ char smem[32768];
  u16* lsA = (u16*)smem;
  u16* lsB = (u16*)(smem + 16384);
  const int nt = blockIdx.x, n0 = nt * 64;
  const int tid = threadIdx.x, w = tid >> 6, l = tid & 63;
  const int lr = l & 15, lq = l >> 4;
  f32x4 acc[4] = {};
  for (int kt = 0; kt < 16; ++kt) {
#pragma unroll
    for (int i = 0; i < 4; ++i) {
      int rb = w * 16 + i * 4;
      const u16* ga = hprev + (size_t)(rb + (l >> 4)) * 2048 + kt * 128 + (l & 15) * 8;
      __builtin_amdgcn_global_load_lds(
          (const __attribute__((address_space(1))) void*)ga,
          (__attribute__((address_space(3))) void*)(lsA + rb * 128), 16, 0, 0);
      const u16* gb = Wb + (size_t)(n0 + rb + (l >> 4)) * 2048 + kt * 128 + (l & 15) * 8;
      __builtin_amdgcn_global_load_lds(
          (const __attribute__((address_space(1))) void*)gb,
          (__attribute__((address_space(3))) void*)(lsB + rb * 128), 16, 0, 0);
    }
    asm volatile("s_waitcnt vmcnt(0)" ::: "memory");
    __syncthreads();
    bf16x8 af[4];
    int ar = w * 16 + lr;
#pragma unroll
    for (int s = 0; s < 4; ++s)
      af[s] = *(const bf16x8*)&lsA[ar * 128 + (s >> 1) * 64 + ((((s & 1) << 2) + lq) ^ (ar & 7)) * 8];
#pragma unroll
    for (int j = 0; j < 4; ++j) {
      int br = j * 16 + lr;
#pragma unroll
      for (int s = 0; s < 4; ++s) {
        bf16x8 bv = *(const bf16x8*)&lsB[br * 128 + (s >> 1) * 64 + ((((s & 1) << 2) + lq) ^ (br & 7)) * 8];
        acc[j] = __builtin_amdgcn_mfma_f32_16x16x32_bf16(af[s], bv, acc[j], 0, 0, 0);
      }
    }
    __syncthreads();
  }
  float* gsh = (float*)smem;
#pragma unroll
  for (int j = 0; j < 4; ++j)
#pragma unroll
    for (int rr = 0; rr < 4; ++rr)
      gsh[(w * 16 + lq * 4 + rr) * 68 + j * 16 + lr] = acc[j][rr];
  __syncthreads();
  const int ui = tid & 15, mq = tid >> 4;
#pragma unroll
  for (int mr = 0; mr < 4; ++mr) {
    int m = mr * 16 + mq;
    float gi = gsh[m * 68 + 0 + ui]  + xg[(size_t)m * G_ + n0 + 0 + ui];
    float gf = gsh[m * 68 + 16 + ui] + xg[(size_t)m * G_ + n0 + 16 + ui];
    float gg = gsh[m * 68 + 32 + ui] + xg[(size_t)m * G_ + n0 + 32 + ui];
    float go = gsh[m * 68 + 48 + ui] + xg[(size_t)m * G_ + n0 + 48 + ui];
    int unit = nt * 16 + ui;
    int ci = m * H_ + unit;
    float cn = sigm(gf) * c[ci] + sigm(gi) * tanhf(gg);
    float hn = sigm(go) * tanhf(cn);
    c[ci] = cn;
    hf[ci] = hn;
    if (EMIT_F32) hsf[ci] = hn;
    u16 hh = bf16_rn(hn);
    u16 hl = bf16_rn(hn - bf16_f(hh));
    size_t oh = (size_t)m * 2048 + ((unit >> 6) << 6) +
                ((((unit >> 3) & 7) ^ (m & 7)) << 3) + (unit & 7);
    hbf_out[oh] = hh;
    hbf_out[oh + 1024] = hl;
  }
}

// ---------------------------------------------------------------------------
extern "C" void kernel_launch(void* const* d_in, const int* in_sizes, int n_in,
                              void* d_out, int out_size, void* d_ws, size_t ws_size,
                              hipStream_t stream) {
  const int*   word  = (const int*)  d_in[0];
  const int*   seq   = (const int*)  d_in[1];
  const float* emb   = (const float*)d_in[2];
  const float* w2h_W = (const float*)d_in[3];
  const float* w2h_b = (const float*)d_in[4];
  const float* W_ih0 = (const float*)d_in[5];
  const float* W_hh0 = (const float*)d_in[6];
  const float* b_ih0 = (const float*)d_in[7];
  const float* b_hh0 = (const float*)d_in[8];
  const float* W_ih1 = (const float*)d_in[9];
  const float* W_hh1 = (const float*)d_in[10];
  const float* b_ih1 = (const float*)d_in[11];
  const float* b_hh1 = (const float*)d_in[12];
  const float* dec_W = (const float*)d_in[13];
  const float* dec_b = (const float*)d_in[14];

  float* out = (float*)d_out;
  float* hL0 = out + 102400000;
  float* hL1 = hL0 + B_ * H_;
  float* cL0 = out + 102531072;
  float* cL1 = cL0 + B_ * H_;

  // scratch in d_out (clobber-safe: decoder writes [0,102.4M) last)
  float* xg0      = out;                       // [3200,4096]
  u16*   x0w_bf   = (u16*)(out + 13200000);    // [64,2048]
  u16*   x0seq_bf = (u16*)(out + 13300000);    // [3200,2048]
  u16*   hs0slots = (u16*)(out + 16600000);    // [51][64][2048] (slot0 zeros)
  u16*   wih0a_bf = (u16*)(out + 20000000);    // [4096,2048] each
  u16*   wih0b_bf = (u16*)(out + 24200000);
  u16*   wih1_bf  = (u16*)(out + 28400000);
  u16*   whh0_bf  = (u16*)(out + 32600000);
  u16*   whh1_bf  = (u16*)(out + 36800000);
  float* y_w      = out + 73800000;            // [64,4096]
  float* bias0p   = out + 74400000;
  float* bias1p   = out + 74410000;
  float* xg1      = out + 87560192;            // [3200,4096]
  unsigned* bar0  = (unsigned*)(out + 101000000);
  unsigned* bar1  = (unsigned*)(out + 101000032);
  u16*   hbfA     = (u16*)(out + 101100000);   // tiny path ping-pong
  u16*   hbfB     = (u16*)(out + 101200000);

  const size_t need_hs1  = (size_t)T_ * B_ * H_ * 4;                       // 13.1 MB
  const size_t need_full = (size_t)V_ * 2048 * 2 + (size_t)(T_ + 1) * B_ * 2048 * 2;
  const bool tier1 = ws_size >= need_full;
  const bool tier2 = !tier1 && ws_size >= need_hs1;

  u16*   decW_bf  = (u16*)d_ws;                              // tier1
  u16*   hs1slots = (u16*)d_ws + (size_t)V_ * 2048;          // tier1
  float* hs1f     = (float*)d_ws;                            // tier2

  // init
  fill_zero<<<1, 128, 0, stream>>>(out + 101000000, 128);         // barriers
  fill_zero<<<256, 256, 0, stream>>>((float*)hs0slots, 65536);    // slot 0
  if (tier1) fill_zero<<<256, 256, 0, stream>>>((float*)hs1slots, 65536);
  bias_perm<<<16, 256, 0, stream>>>(b_ih0, b_hh0, bias0p);
  bias_perm<<<16, 256, 0, stream>>>(b_ih1, b_hh1, bias1p);

  // c0 = word_emb @ w2h_W^T + w2h_b (both layers)
  gemm_nt<64, 64, 16, 4, 4><<<dim3(16, 1), 256, 0, stream>>>(
      emb, word, E_, w2h_W, E_, 0, w2h_b, nullptr, 0, -1, cL0, H_, B_, H_, E_);
  gemm_nt<64, 64, 16, 4, 4><<<dim3(16, 1), 256, 0, stream>>>(
      emb, word, E_, w2h_W, E_, 0, w2h_b, nullptr, 0, -1, cL1, H_, B_, H_, E_);

  // conversions to hi|lo bf16 (chunk-permuted)
  conv_w<<<2048, 256, 0, stream>>>(W_ih0, 2 * E_, 0,  nullptr, 1, G_, wih0a_bf);
  conv_w<<<2048, 256, 0, stream>>>(W_ih0, 2 * E_, E_, nullptr, 1, G_, wih0b_bf);
  conv_w<<<2048, 256, 0, stream>>>(W_ih1, H_, 0, nullptr, 1, G_, wih1_bf);
  conv_w<<<2048, 256, 0, stream>>>(W_hh0, H_, 0, nullptr, 1, G_, whh0_bf);
  conv_w<<<2048, 256, 0, stream>>>(W_hh1, H_, 0, nullptr, 1, G_, whh1_bf);
  conv_w<<<32,   256, 0, stream>>>(emb, E_, 0, word, 0, B_, x0w_bf);
  conv_w<<<1600, 256, 0, stream>>>(emb, E_, 0, seq, 0, T_ * B_, x0seq_bf);
  if (tier1)
    conv_w<<<16000, 256, 0, stream>>>(dec_W, H_, 0, nullptr, 0, V_, decW_bf);

  // y_w, xg0
  gemm_bt<<<32, 256, 0, stream>>>(x0w_bf, B_, wih0a_bf, bias0p,
                                  nullptr, 0, -1, y_w, G_, G_, 32);
  gemm_bt<<<800, 256, 0, stream>>>(x0seq_bf, T_ * B_, wih0b_bf, nullptr,
                                   y_w, G_, 63, xg0, G_, G_, 32);

  // ---- layer 0: persistent recurrence ----
  {
    void* dummy = nullptr;
    rnn_pers<false><<<128, 128, 0, stream>>>(
        whh0_bf, xg0, cL0, hL0, hs0slots, (float*)dummy, bar0, T_);
  }

  // xg1 = hs0 @ Wih1^T + bias1p  (slots 1..50 are timesteps 0..49)
  gemm_bt<<<800, 256, 0, stream>>>(hs0slots + B_ * 2048, T_ * B_, wih1_bf, bias1p,
                                   nullptr, 0, -1, xg1, G_, G_, 32);

  if (tier1) {
    rnn_pers<false><<<128, 128, 0, stream>>>(
        whh1_bf, xg1, cL1, hL1, hs1slots, nullptr, bar1, T_);
    gemm_bt<<<6250, 256, 0, stream>>>(hs1slots + B_ * 2048, T_ * B_, decW_bf, dec_b,
                                      nullptr, 0, -1, out, V_, V_, 250);
  } else if (tier2) {
    // layer-1 slots reuse hs0 region (xg1 already consumed it)
    rnn_pers<true><<<128, 128, 0, stream>>>(
        whh1_bf, xg1, cL1, hL1, hs0slots, hs1f, bar1, T_);
    gemm_sp<false, false><<<6250, 256, 0, stream>>>(
        hs1f, nullptr, H_, dec_W, H_, 0, dec_b, nullptr, 0, -1,
        out, V_, T_ * B_, V_, H_, 250);
  } else {
    // tiny-ws: per-step layer1 + per-step decode from live h
    for (int t = 0; t < T_; ++t) {
      const u16* hp = t ? ((t & 1) ? hbfA : hbfB) : hs0slots;  // slot0 zeros
      u16* ho = (t & 1) ? hbfB : hbfA;
      rnn_step<false><<<64, 256, 0, stream>>>(
          hp, whh1_bf, xg1 + (size_t)t * B_ * G_, cL1, hL1, ho, nullptr);
      gemm_sp<false, false><<<250, 256, 0, stream>>>(
          hL1, nullptr, H_, dec_W, H_, 0, dec_b, nullptr, 0, -1,
          out + (size_t)t * B_ * V_, V_, B_, V_, H_, 250);
    }
  }
}

// Round 6
// 3715.466 us; speedup vs baseline: 1.0439x; 1.0439x over previous
//
#include <hip/hip_runtime.h>
#include <cstddef>

// ---------------------------------------------------------------------------
// RNNModel round 6: flag-synced persistent recurrence (no RMW barrier storm),
// triple-buffered staging; pure-bf16 hi|lo K=2048 MFMA GEMMs elsewhere.
// Gate perm: out col n <-> W row perm_g(n)=((n>>4)&3)*1024+(n>>6)*16+(n&15)
// Chunk perm: within each 128B row-segment, 16B chunk c stored at c^(row&7).
// ---------------------------------------------------------------------------

static constexpr int T_ = 50, B_ = 64, E_ = 1024, H_ = 1024, V_ = 32000;
static constexpr int G_ = 4096;

typedef unsigned short u16;
typedef __attribute__((ext_vector_type(8))) short bf16x8;
typedef __attribute__((ext_vector_type(8))) unsigned short u16x8;
typedef __attribute__((ext_vector_type(4))) float f32x4;

__device__ __forceinline__ int perm_g(int n) {
  return ((n >> 4) & 3) * H_ + (n >> 6) * 16 + (n & 15);
}
__device__ __forceinline__ u16 bf16_rn(float x) {
  union { float f; unsigned u; } a; a.f = x;
  unsigned r = a.u + 0x7fffu + ((a.u >> 16) & 1u);
  return (u16)(r >> 16);
}
__device__ __forceinline__ float bf16_f(u16 h) {
  union { float f; unsigned u; } a; a.u = ((unsigned)h) << 16;
  return a.f;
}
__device__ __forceinline__ float sigm(float x) { return 1.f / (1.f + __expf(-x)); }

__global__ void fill_zero(float* p, int n) {
  int i = blockIdx.x * blockDim.x + threadIdx.x;
  if (i < n) p[i] = 0.f;
}
__global__ void vec_add(float* dst, const float* a, const float* b, int n) {
  int i = blockIdx.x * blockDim.x + threadIdx.x;
  if (i < n) dst[i] = a[i] + b[i];
}
__global__ void bias_perm(const float* a, const float* b, float* dst) {
  int n = blockIdx.x * 256 + threadIdx.x;
  int s = perm_g(n);
  dst[n] = a[s] + b[s];
}

// f32 -> bf16 hi|lo [rows x 2048] with chunk permute.
__global__ void conv_w(const float* __restrict__ src, int srcld, int coloff,
                       const int* __restrict__ gidx, int PERM, int rows,
                       u16* __restrict__ dst) {
  int idx = blockIdx.x * 256 + threadIdx.x;
  int r = idx >> 7, kc = (idx & 127) << 3;
  if (r >= rows) return;
  int s = gidx ? gidx[r] : (PERM ? perm_g(r) : r);
  const float* p = src + (size_t)s * srcld + coloff + kc;
  float4 v0 = *(const float4*)p, v1 = *(const float4*)(p + 4);
  float vv[8] = {v0.x, v0.y, v0.z, v0.w, v1.x, v1.y, v1.z, v1.w};
  u16x8 hi, lo;
#pragma unroll
  for (int i = 0; i < 8; ++i) {
    u16 h = bf16_rn(vv[i]);
    hi[i] = h;
    lo[i] = bf16_rn(vv[i] - bf16_f(h));
  }
  size_t o = (size_t)r * 2048 + ((kc >> 6) << 6) + ((((kc >> 3) & 7) ^ (r & 7)) << 3);
  *(u16x8*)&dst[o] = hi;
  *(u16x8*)&dst[o + 1024] = lo;
}

// ------------------------- fp32 tiled GEMM (c0 init) ------------------------
template<int BM, int BN, int BK, int TM, int TN>
__launch_bounds__(256)
__global__ void gemm_nt(
    const float* __restrict__ A, const int* __restrict__ Aidx, int lda,
    const float* __restrict__ W, int ldw, int koff,
    const float* __restrict__ bias,
    const float* __restrict__ Dadd, int ldd, int dmask,
    float* __restrict__ C, int ldc, int M, int N, int K) {
  constexpr int TX = BN / TN;
  constexpr int TY = BM / TM;
  static_assert(TX * TY == 256, "thread geometry");
  __shared__ float As[BK][BM + 4];
  __shared__ float Ws[BK][BN + 4];
  const int tid = threadIdx.x;
  const int tx = tid % TX, ty = tid / TX;
  const int m0 = blockIdx.y * BM, n0 = blockIdx.x * BN;
  float acc[TM][TN];
#pragma unroll
  for (int i = 0; i < TM; ++i)
#pragma unroll
    for (int j = 0; j < TN; ++j) acc[i][j] = 0.f;
  constexpr int AV = (BM * BK) / 4;
  constexpr int WV = (BN * BK) / 4;
  constexpr int KV = BK / 4;
  for (int k0 = 0; k0 < K; k0 += BK) {
#pragma unroll
    for (int lp = 0; lp < (AV + 255) / 256; ++lp) {
      int e = tid + lp * 256;
      if (e < AV) {
        int r = e / KV, kq = e % KV;
        int m = m0 + r;
        float4 v = make_float4(0.f, 0.f, 0.f, 0.f);
        if (m < M) {
          int row = Aidx ? Aidx[m] : m;
          v = *(const float4*)&A[(size_t)row * lda + k0 + kq * 4];
        }
        As[kq * 4 + 0][r] = v.x; As[kq * 4 + 1][r] = v.y;
        As[kq * 4 + 2][r] = v.z; As[kq * 4 + 3][r] = v.w;
      }
    }
#pragma unroll
    for (int lp = 0; lp < (WV + 255) / 256; ++lp) {
      int e = tid + lp * 256;
      if (e < WV) {
        int cc = e / KV, kq = e % KV;
        int n = n0 + cc;
        float4 v = make_float4(0.f, 0.f, 0.f, 0.f);
        if (n < N)
          v = *(const float4*)&W[(size_t)n * ldw + koff + k0 + kq * 4];
        Ws[kq * 4 + 0][cc] = v.x; Ws[kq * 4 + 1][cc] = v.y;
        Ws[kq * 4 + 2][cc] = v.z; Ws[kq * 4 + 3][cc] = v.w;
      }
    }
    __syncthreads();
#pragma unroll
    for (int kk = 0; kk < BK; ++kk) {
      float a[TM], b[TN];
#pragma unroll
      for (int i = 0; i < TM; ++i) a[i] = As[kk][ty * TM + i];
#pragma unroll
      for (int j = 0; j < TN; ++j) b[j] = Ws[kk][tx * TN + j];
#pragma unroll
      for (int i = 0; i < TM; ++i)
#pragma unroll
        for (int j = 0; j < TN; ++j)
          acc[i][j] += a[i] * b[j];
    }
    __syncthreads();
  }
#pragma unroll
  for (int i = 0; i < TM; ++i) {
    int m = m0 + ty * TM + i;
    if (m >= M) continue;
#pragma unroll
    for (int j = 0; j < TN; ++j) {
      int n = n0 + tx * TN + j;
      if (n >= N) continue;
      float v = acc[i][j];
      if (bias) v += bias[n];
      if (Dadd) {
        int dr = (dmask < 0) ? m : (m & dmask);
        v += Dadd[(size_t)dr * ldd + n];
      }
      C[(size_t)m * ldc + n] = v;
    }
  }
}

// ----------------- pure-bf16 MFMA GEMM: C = A @ Wb^T (+bias)(+Dadd) --------
// ord=0: bx=wg%nbx (N-fast); ord=1: by=wg%mt (M-fast, B-slice L2-resident)
__launch_bounds__(256)
__global__ void gemm_bt(const u16* __restrict__ A, int Mrows,
                        const u16* __restrict__ Wb,
                        const float* __restrict__ bias,
                        const float* __restrict__ Dadd, int ldd, int dmask,
                        float* __restrict__ C, int ldc, int N, int nbx,
                        int mt, int ord) {
  __shared__ u16 lsA[128 * 64];
  __shared__ u16 lsB[128 * 64];

  int nwg = gridDim.x, bid = blockIdx.x;
  int q = nwg >> 3, r = nwg & 7;
  int xcd = bid & 7, base = bid >> 3;
  int wg = (xcd < r ? xcd * (q + 1) : r * (q + 1) + (xcd - r) * q) + base;
  int bx, by;
  if (ord) { by = wg % mt; bx = wg / mt; } else { bx = wg % nbx; by = wg / nbx; }
  const int m0 = by * 128, n0 = bx * 128;

  const int tid = threadIdx.x, w = tid >> 6, l = tid & 63;
  const int lr = l & 15, lq = l >> 4;
  const int wm = (w >> 1) * 64, wn = (w & 1) * 64;

  f32x4 acc[4][4] = {};

  for (int kt = 0; kt < 32; ++kt) {
#pragma unroll
    for (int i = 0; i < 4; ++i) {
      int rb = w * 32 + i * 8;
      int gm = m0 + rb + (l >> 3);
      if (gm > Mrows - 1) gm = Mrows - 1;
      const u16* ga = A + (size_t)gm * 2048 + kt * 64 + (l & 7) * 8;
      __builtin_amdgcn_global_load_lds(
          (const __attribute__((address_space(1))) void*)ga,
          (__attribute__((address_space(3))) void*)(lsA + rb * 64), 16, 0, 0);
      const u16* gb = Wb + (size_t)(n0 + rb + (l >> 3)) * 2048 + kt * 64 + (l & 7) * 8;
      __builtin_amdgcn_global_load_lds(
          (const __attribute__((address_space(1))) void*)gb,
          (__attribute__((address_space(3))) void*)(lsB + rb * 64), 16, 0, 0);
    }
    asm volatile("s_waitcnt vmcnt(0)" ::: "memory");
    __syncthreads();

    bf16x8 af[4][2], bfr[4][2];
#pragma unroll
    for (int i = 0; i < 4; ++i) {
      int ar = wm + i * 16 + lr;
#pragma unroll
      for (int s = 0; s < 2; ++s)
        af[i][s] = *(const bf16x8*)&lsA[ar * 64 + (((s << 2) + lq) ^ (ar & 7)) * 8];
    }
#pragma unroll
    for (int j = 0; j < 4; ++j) {
      int br = wn + j * 16 + lr;
#pragma unroll
      for (int s = 0; s < 2; ++s)
        bfr[j][s] = *(const bf16x8*)&lsB[br * 64 + (((s << 2) + lq) ^ (br & 7)) * 8];
    }
#pragma unroll
    for (int i = 0; i < 4; ++i)
#pragma unroll
      for (int j = 0; j < 4; ++j) {
        acc[i][j] = __builtin_amdgcn_mfma_f32_16x16x32_bf16(af[i][0], bfr[j][0], acc[i][j], 0, 0, 0);
        acc[i][j] = __builtin_amdgcn_mfma_f32_16x16x32_bf16(af[i][1], bfr[j][1], acc[i][j], 0, 0, 0);
      }
    __syncthreads();
  }

#pragma unroll
  for (int i = 0; i < 4; ++i) {
    int mbase = m0 + wm + i * 16 + lq * 4;
#pragma unroll
    for (int j = 0; j < 4; ++j) {
      int n = n0 + wn + j * 16 + lr;
      float badd = bias ? bias[n] : 0.f;
#pragma unroll
      for (int rr = 0; rr < 4; ++rr) {
        int m = mbase + rr;
        if (m >= Mrows) continue;
        float v = acc[i][j][rr] + badd;
        if (Dadd) {
          int dr = (dmask < 0) ? m : (m & dmask);
          v += Dadd[(size_t)dr * ldd + n];
        }
        C[(size_t)m * ldc + n] = v;
      }
    }
  }
}

// ----------- split-bf16 MFMA GEMM on f32 inputs (tier2/tiny decoder) -------
template<bool GATHER, bool WPERM>
__launch_bounds__(256)
__global__ void gemm_sp(
    const float* __restrict__ A, const int* __restrict__ Aidx, int lda,
    const float* __restrict__ W, int ldw, int koff,
    const float* __restrict__ bias,
    const float* __restrict__ Dadd, int ldd, int dmask,
    float* __restrict__ C, int ldc, int M, int N, int K, int nbx) {
  __shared__ u16 As_h[128][40], As_l[128][40];
  __shared__ u16 Ws_h[128][40], Ws_l[128][40];
  int nwg = gridDim.x, bid = blockIdx.x;
  int q = nwg >> 3, r = nwg & 7;
  int xcd = bid & 7, base = bid >> 3;
  int wg = (xcd < r ? xcd * (q + 1) : r * (q + 1) + (xcd - r) * q) + base;
  int bx = wg % nbx, by = wg / nbx;
  const int m0 = by * 128, n0 = bx * 128;
  const int tid = threadIdx.x;
  const int wave = tid >> 6, lane = tid & 63;
  const int lr = lane & 15, lq = lane >> 4;
  const int wm = (wave >> 1) * 64, wn = (wave & 1) * 64;
  f32x4 acc[4][4] = {};
  for (int k0 = 0; k0 < K; k0 += 32) {
#pragma unroll
    for (int lp = 0; lp < 4; ++lp) {
      int s = tid + lp * 256;
      int row = s >> 3, kq = s & 7;
      float4 v = make_float4(0.f, 0.f, 0.f, 0.f);
      int gm = m0 + row;
      if (gm < M) {
        int src = GATHER ? Aidx[gm] : gm;
        v = *(const float4*)&A[(size_t)src * lda + k0 + kq * 4];
      }
      u16 h0 = bf16_rn(v.x), h1 = bf16_rn(v.y), h2 = bf16_rn(v.z), h3 = bf16_rn(v.w);
      u16 l0 = bf16_rn(v.x - bf16_f(h0)), l1 = bf16_rn(v.y - bf16_f(h1));
      u16 l2 = bf16_rn(v.z - bf16_f(h2)), l3 = bf16_rn(v.w - bf16_f(h3));
      *(uint2*)&As_h[row][kq * 4] =
          make_uint2((unsigned)h0 | ((unsigned)h1 << 16), (unsigned)h2 | ((unsigned)h3 << 16));
      *(uint2*)&As_l[row][kq * 4] =
          make_uint2((unsigned)l0 | ((unsigned)l1 << 16), (unsigned)l2 | ((unsigned)l3 << 16));
    }
#pragma unroll
    for (int lp = 0; lp < 4; ++lp) {
      int s = tid + lp * 256;
      int col = s >> 3, kq = s & 7;
      int n = n0 + col;
      float4 v = make_float4(0.f, 0.f, 0.f, 0.f);
      if (n < N) {
        int srow = WPERM ? perm_g(n) : n;
        v = *(const float4*)&W[(size_t)srow * ldw + koff + k0 + kq * 4];
      }
      u16 h0 = bf16_rn(v.x), h1 = bf16_rn(v.y), h2 = bf16_rn(v.z), h3 = bf16_rn(v.w);
      u16 l0 = bf16_rn(v.x - bf16_f(h0)), l1 = bf16_rn(v.y - bf16_f(h1));
      u16 l2 = bf16_rn(v.z - bf16_f(h2)), l3 = bf16_rn(v.w - bf16_f(h3));
      *(uint2*)&Ws_h[col][kq * 4] =
          make_uint2((unsigned)h0 | ((unsigned)h1 << 16), (unsigned)h2 | ((unsigned)h3 << 16));
      *(uint2*)&Ws_l[col][kq * 4] =
          make_uint2((unsigned)l0 | ((unsigned)l1 << 16), (unsigned)l2 | ((unsigned)l3 << 16));
    }
    __syncthreads();
    bf16x8 ah[4], al[4], bh[4], bl[4];
#pragma unroll
    for (int i = 0; i < 4; ++i) {
      ah[i] = *(const bf16x8*)&As_h[wm + i * 16 + lr][lq * 8];
      al[i] = *(const bf16x8*)&As_l[wm + i * 16 + lr][lq * 8];
    }
#pragma unroll
    for (int j = 0; j < 4; ++j) {
      bh[j] = *(const bf16x8*)&Ws_h[wn + j * 16 + lr][lq * 8];
      bl[j] = *(const bf16x8*)&Ws_l[wn + j * 16 + lr][lq * 8];
    }
#pragma unroll
    for (int i = 0; i < 4; ++i)
#pragma unroll
      for (int j = 0; j < 4; ++j) {
        acc[i][j] = __builtin_amdgcn_mfma_f32_16x16x32_bf16(ah[i], bh[j], acc[i][j], 0, 0, 0);
        acc[i][j] = __builtin_amdgcn_mfma_f32_16x16x32_bf16(ah[i], bl[j], acc[i][j], 0, 0, 0);
        acc[i][j] = __builtin_amdgcn_mfma_f32_16x16x32_bf16(al[i], bh[j], acc[i][j], 0, 0, 0);
      }
    __syncthreads();
  }
#pragma unroll
  for (int i = 0; i < 4; ++i) {
    int mbase = m0 + wm + i * 16 + lq * 4;
#pragma unroll
    for (int j = 0; j < 4; ++j) {
      int n = n0 + wn + j * 16 + lr;
      if (n >= N) continue;
      float badd = bias ? bias[WPERM ? perm_g(n) : n] : 0.f;
#pragma unroll
      for (int rr = 0; rr < 4; ++rr) {
        int m = mbase + rr;
        if (m >= M) continue;
        float v = acc[i][j][rr] + badd;
        if (Dadd) {
          int dr = (dmask < 0) ? m : (m & dmask);
          v += Dadd[(size_t)dr * ldd + n];
        }
        C[(size_t)m * ldc + n] = v;
      }
    }
  }
}

// ---------------- persistent recurrence v2: flag sync, no RMW ---------------
// 64 blocks x 256 thr (4 waves). bid: x=bid&7, i=bid>>3; rg=i&1 (32 rows),
// ct=x*4+(i>>1) (128 gate-cols = 32 units). XCD x holds ct in [4x,4x+4):
// 4 x 512KB Whh slices L2-resident. Sync: writer (rg,ct) release-stores
// flag[rg*32+ct]=t+1 (own 128B line); reader polls its rg's 32 flags with a
// 32-lane vector acquire load. Triple-buffered gload_lds staging (BK=128).
template<bool EMIT>
__launch_bounds__(256, 1)
__global__ void rnn_pers2(const u16* __restrict__ Wb, const float* __restrict__ xgall,
                          float* __restrict__ cL, float* __restrict__ hL,
                          u16* __restrict__ hs, float* __restrict__ hsf,
                          unsigned* __restrict__ flags, int T) {
  __shared__ u16 lsA[3][32 * 128];    // 24 KB
  __shared__ u16 lsB[3][128 * 128];   // 96 KB

  const int bid = blockIdx.x;
  const int x = bid & 7, i = bid >> 3;
  const int rg = i & 1;
  const int ct = x * 4 + (i >> 1);
  const int m0 = rg * 32, n0 = ct * 128;
  const int tid = threadIdx.x, w = tid >> 6, l = tid & 63;
  const int lr = l & 15, lq = l >> 4;
  const int wr = w >> 1, wg = w & 1;

  const u16* WbB = Wb + (size_t)n0 * 2048;

  const int mb = m0 + wr * 16 + lq * 4;   // first of this thread's 4 rows
  const int u = ct * 32 + wg * 16 + lr;   // this thread's unit
  float creg[4];
#pragma unroll
  for (int rr = 0; rr < 4; ++rr) creg[rr] = cL[(mb + rr) * H_ + u];

  for (int t = 0; t < T; ++t) {
    // ---- wait for previous step's h (slot t) from this rg's 32 writers
    if (t) {
      const unsigned tgt = (unsigned)t;
      int guard = 0;
      for (;;) {
        unsigned v = tgt;
        if (l < 32)
          v = __hip_atomic_load(flags + (size_t)(rg * 32 + l) * 32,
                                __ATOMIC_ACQUIRE, __HIP_MEMORY_SCOPE_AGENT);
        if (__all(v >= tgt)) break;
        if (++guard > (1 << 24)) break;
        __builtin_amdgcn_s_sleep(1);
      }
    }
    __syncthreads();   // also guards LDS buffer reuse across steps

    const u16* hp = hs + (size_t)t * (B_ * 2048);
    const float* xg = xgall + (size_t)t * ((size_t)B_ * G_);

    f32x4 acc[4] = {};

    // staging: per wave 2 A-loads + 8 B-loads per chunk
#define STAGE(KC, BUF)                                                          \
    {                                                                           \
      const int kb_ = (KC) * 128;                                               \
      _Pragma("unroll")                                                         \
      for (int i4 = 0; i4 < 2; ++i4) {                                          \
        int ra = w * 8 + i4 * 4;                                                \
        const u16* ga = hp + (size_t)(m0 + ra + (l >> 4)) * 2048 + kb_ + (l & 15) * 8; \
        __builtin_amdgcn_global_load_lds(                                       \
            (const __attribute__((address_space(1))) void*)ga,                  \
            (__attribute__((address_space(3))) void*)(&lsA[BUF][ra * 128]), 16, 0, 0); \
      }                                                                         \
      _Pragma("unroll")                                                         \
      for (int i4 = 0; i4 < 8; ++i4) {                                          \
        int rb = w * 32 + i4 * 4;                                               \
        const u16* gb = WbB + (size_t)(rb + (l >> 4)) * 2048 + kb_ + (l & 15) * 8; \
        __builtin_amdgcn_global_load_lds(                                       \
            (const __attribute__((address_space(1))) void*)gb,                  \
            (__attribute__((address_space(3))) void*)(&lsB[BUF][rb * 128]), 16, 0, 0); \
      }                                                                         \
    }

    STAGE(0, 0)
    STAGE(1, 1)

    for (int kc = 0; kc < 16; ++kc) {
      const int cur = kc % 3;
      if (kc < 14) {
        STAGE(kc + 2, (kc + 2) % 3)
        asm volatile("s_waitcnt vmcnt(20)" ::: "memory");
      } else if (kc == 14) {
        asm volatile("s_waitcnt vmcnt(10)" ::: "memory");
      } else {
        asm volatile("s_waitcnt vmcnt(0)" ::: "memory");
      }
      __syncthreads();

      bf16x8 af[4];
      const int ar = wr * 16 + lr;   // local A row (m0 multiple of 32 -> &7 ok)
#pragma unroll
      for (int ks = 0; ks < 4; ++ks)
        af[ks] = *(const bf16x8*)&lsA[cur][ar * 128 + (ks >> 1) * 64 +
                                           ((((ks & 1) << 2) + lq) ^ (ar & 7)) * 8];
#pragma unroll
      for (int j = 0; j < 4; ++j) {
        const int br = wg * 64 + j * 16 + lr;
#pragma unroll
        for (int ks = 0; ks < 4; ++ks) {
          bf16x8 bv = *(const bf16x8*)&lsB[cur][br * 128 + (ks >> 1) * 64 +
                                                ((((ks & 1) << 2) + lq) ^ (br & 7)) * 8];
          acc[j] = __builtin_amdgcn_mfma_f32_16x16x32_bf16(af[ks], bv, acc[j], 0, 0, 0);
        }
      }
      __syncthreads();
    }
#undef STAGE

    // ---- LSTM cell: acc[j][rr] = gate j of (row mb+rr, unit u)
    float xgv[4][4];
#pragma unroll
    for (int rr = 0; rr < 4; ++rr)
#pragma unroll
      for (int g = 0; g < 4; ++g)
        xgv[rr][g] = xg[(size_t)(mb + rr) * G_ + n0 + wg * 64 + g * 16 + lr];

    u16* hnext = hs + (size_t)(t + 1) * (B_ * 2048);
#pragma unroll
    for (int rr = 0; rr < 4; ++rr) {
      const int m = mb + rr;
      float gi = acc[0][rr] + xgv[rr][0];
      float gf = acc[1][rr] + xgv[rr][1];
      float gg = acc[2][rr] + xgv[rr][2];
      float go = acc[3][rr] + xgv[rr][3];
      float cn = sigm(gf) * creg[rr] + sigm(gi) * tanhf(gg);
      float hn = sigm(go) * tanhf(cn);
      creg[rr] = cn;
      if (EMIT) hsf[(size_t)t * (B_ * H_) + m * H_ + u] = hn;
      if (t == T - 1) { cL[m * H_ + u] = cn; hL[m * H_ + u] = hn; }
      u16 hh = bf16_rn(hn);
      u16 hl2 = bf16_rn(hn - bf16_f(hh));
      size_t oh = (size_t)m * 2048 + ((u >> 6) << 6) +
                  ((((u >> 3) & 7) ^ (m & 7)) << 3) + (u & 7);
      hnext[oh] = hh;
      hnext[oh + 1024] = hl2;
    }

    // ---- publish
    if (t < T - 1) {
      __threadfence();
      __syncthreads();
      if (tid == 0)
        __hip_atomic_store(flags + (size_t)(rg * 32 + ct) * 32, (unsigned)(t + 1),
                           __ATOMIC_RELEASE, __HIP_MEMORY_SCOPE_AGENT);
    }
  }
}

// --------- single-step kernel (tiny-ws fallback) ---------------------------
template<bool EMIT_F32>
__launch_bounds__(256)
__global__ void rnn_step(const u16* __restrict__ hprev, const u16* __restrict__ Wb,
                         const float* __restrict__ xg,
                         float* __restrict__ c, float* __restrict__ hf,
                         u16* __restrict__ hbf_out, float* __restrict__ hsf) {
  __shared__ char smem[32768];
  u16* lsA = (u16*)smem;
  u16* lsB = (u16*)(smem + 16384);
  const int nt = blockIdx.x, n0 = nt * 64;
  const int tid = threadIdx.x, w = tid >> 6, l = tid & 63;
  const int lr = l & 15, lq = l >> 4;
  f32x4 acc[4] = {};
  for (int kt = 0; kt < 16; ++kt) {
#pragma unroll
    for (int i = 0; i < 4; ++i) {
      int rb = w * 16 + i * 4;
      const u16* ga = hprev + (size_t)(rb + (l >> 4)) * 2048 + kt * 128 + (l & 15) * 8;
      __builtin_amdgcn_global_load_lds(
          (const __attribute__((address_space(1))) void*)ga,
          (__attribute__((address_space(3))) void*)(lsA + rb * 128), 16, 0, 0);
      const u16* gb = Wb + (size_t)(n0 + rb + (l >> 4)) * 2048 + kt * 128 + (l & 15) * 8;
      __builtin_amdgcn_global_load_lds(
          (const __attribute__((address_space(1))) void*)gb,
          (__attribute__((address_space(3))) void*)(lsB + rb * 128), 16, 0, 0);
    }
    asm volatile("s_waitcnt vmcnt(0)" ::: "memory");
    __syncthreads();
    bf16x8 af[4];
    int ar = w * 16 + lr;
#pragma unroll
    for (int s = 0; s < 4; ++s)
      af[s] = *(const bf16x8*)&lsA[ar * 128 + (s >> 1) * 64 + ((((s & 1) << 2) + lq) ^ (ar & 7)) * 8];
#pragma unroll
    for (int j = 0; j < 4; ++j) {
      int br = j * 16 + lr;
#pragma unroll
      for (int s = 0; s < 4; ++s) {
        bf16x8 bv = *(const bf16x8*)&lsB[br * 128 + (s >> 1) * 64 + ((((s & 1) << 2) + lq) ^ (br & 7)) * 8];
        acc[j] = __builtin_amdgcn_mfma_f32_16x16x32_bf16(af[s], bv, acc[j], 0, 0, 0);
      }
    }
    __syncthreads();
  }
  float* gsh = (float*)smem;
#pragma unroll
  for (int j = 0; j < 4; ++j)
#pragma unroll
    for (int rr = 0; rr < 4; ++rr)
      gsh[(w * 16 + lq * 4 + rr) * 68 + j * 16 + lr] = acc[j][rr];
  __syncthreads();
  const int ui = tid & 15, mq = tid >> 4;
#pragma unroll
  for (int mr = 0; mr < 4; ++mr) {
    int m = mr * 16 + mq;
    float gi = gsh[m * 68 + 0 + ui]  + xg[(size_t)m * G_ + n0 + 0 + ui];
    float gf = gsh[m * 68 + 16 + ui] + xg[(size_t)m * G_ + n0 + 16 + ui];
    float gg = gsh[m * 68 + 32 + ui] + xg[(size_t)m * G_ + n0 + 32 + ui];
    float go = gsh[m * 68 + 48 + ui] + xg[(size_t)m * G_ + n0 + 48 + ui];
    int unit = nt * 16 + ui;
    int ci = m * H_ + unit;
    float cn = sigm(gf) * c[ci] + sigm(gi) * tanhf(gg);
    float hn = sigm(go) * tanhf(cn);
    c[ci] = cn;
    hf[ci] = hn;
    if (EMIT_F32) hsf[ci] = hn;
    u16 hh = bf16_rn(hn);
    u16 hl = bf16_rn(hn - bf16_f(hh));
    size_t oh = (size_t)m * 2048 + ((unit >> 6) << 6) +
                ((((unit >> 3) & 7) ^ (m & 7)) << 3) + (unit & 7);
    hbf_out[oh] = hh;
    hbf_out[oh + 1024] = hl;
  }
}

// ---------------------------------------------------------------------------
extern "C" void kernel_launch(void* const* d_in, const int* in_sizes, int n_in,
                              void* d_out, int out_size, void* d_ws, size_t ws_size,
                              hipStream_t stream) {
  const int*   word  = (const int*)  d_in[0];
  const int*   seq   = (const int*)  d_in[1];
  const float* emb   = (const float*)d_in[2];
  const float* w2h_W = (const float*)d_in[3];
  const float* w2h_b = (const float*)d_in[4];
  const float* W_ih0 = (const float*)d_in[5];
  const float* W_hh0 = (const float*)d_in[6];
  const float* b_ih0 = (const float*)d_in[7];
  const float* b_hh0 = (const float*)d_in[8];
  const float* W_ih1 = (const float*)d_in[9];
  const float* W_hh1 = (const float*)d_in[10];
  const float* b_ih1 = (const float*)d_in[11];
  const float* b_hh1 = (const float*)d_in[12];
  const float* dec_W = (const float*)d_in[13];
  const float* dec_b = (const float*)d_in[14];

  float* out = (float*)d_out;
  float* hL0 = out + 102400000;
  float* hL1 = hL0 + B_ * H_;
  float* cL0 = out + 102531072;
  float* cL1 = cL0 + B_ * H_;

  // scratch in d_out (clobber-safe: decoder writes [0,102.4M) last)
  float* xg0      = out;                       // [3200,4096]
  u16*   x0w_bf   = (u16*)(out + 13200000);    // [64,2048]
  u16*   x0seq_bf = (u16*)(out + 13300000);    // [3200,2048]
  u16*   hs0slots = (u16*)(out + 16600000);    // [51][64][2048] (slot0 zeros)
  u16*   wih0a_bf = (u16*)(out + 20000000);    // [4096,2048] each
  u16*   wih0b_bf = (u16*)(out + 24200000);
  u16*   wih1_bf  = (u16*)(out + 28400000);
  u16*   whh0_bf  = (u16*)(out + 32600000);
  u16*   whh1_bf  = (u16*)(out + 36800000);
  float* y_w      = out + 73800000;            // [64,4096]
  float* bias0p   = out + 74400000;
  float* bias1p   = out + 74410000;
  float* xg1      = out + 87560192;            // [3200,4096]
  unsigned* flg0  = (unsigned*)(out + 101000000);  // 64 flags x 32 dwords
  unsigned* flg1  = (unsigned*)(out + 101004096);
  u16*   hbfA     = (u16*)(out + 101100000);   // tiny path ping-pong
  u16*   hbfB     = (u16*)(out + 101200000);

  const size_t need_hs1  = (size_t)T_ * B_ * H_ * 4;
  const size_t need_full = (size_t)V_ * 2048 * 2 + (size_t)(T_ + 1) * B_ * 2048 * 2;
  const bool tier1 = ws_size >= need_full;
  const bool tier2 = !tier1 && ws_size >= need_hs1;

  u16*   decW_bf  = (u16*)d_ws;
  u16*   hs1slots = (u16*)d_ws + (size_t)V_ * 2048;
  float* hs1f     = (float*)d_ws;

  // init
  fill_zero<<<32, 256, 0, stream>>>(out + 101000000, 8192);       // flags
  fill_zero<<<256, 256, 0, stream>>>((float*)hs0slots, 65536);    // slot 0
  if (tier1) fill_zero<<<256, 256, 0, stream>>>((float*)hs1slots, 65536);
  bias_perm<<<16, 256, 0, stream>>>(b_ih0, b_hh0, bias0p);
  bias_perm<<<16, 256, 0, stream>>>(b_ih1, b_hh1, bias1p);

  // c0 = word_emb @ w2h_W^T + w2h_b (both layers)
  gemm_nt<64, 64, 16, 4, 4><<<dim3(16, 1), 256, 0, stream>>>(
      emb, word, E_, w2h_W, E_, 0, w2h_b, nullptr, 0, -1, cL0, H_, B_, H_, E_);
  gemm_nt<64, 64, 16, 4, 4><<<dim3(16, 1), 256, 0, stream>>>(
      emb, word, E_, w2h_W, E_, 0, w2h_b, nullptr, 0, -1, cL1, H_, B_, H_, E_);

  // conversions to hi|lo bf16 (chunk-permuted)
  conv_w<<<2048, 256, 0, stream>>>(W_ih0, 2 * E_, 0,  nullptr, 1, G_, wih0a_bf);
  conv_w<<<2048, 256, 0, stream>>>(W_ih0, 2 * E_, E_, nullptr, 1, G_, wih0b_bf);
  conv_w<<<2048, 256, 0, stream>>>(W_ih1, H_, 0, nullptr, 1, G_, wih1_bf);
  conv_w<<<2048, 256, 0, stream>>>(W_hh0, H_, 0, nullptr, 1, G_, whh0_bf);
  conv_w<<<2048, 256, 0, stream>>>(W_hh1, H_, 0, nullptr, 1, G_, whh1_bf);
  conv_w<<<32,   256, 0, stream>>>(emb, E_, 0, word, 0, B_, x0w_bf);
  conv_w<<<1600, 256, 0, stream>>>(emb, E_, 0, seq, 0, T_ * B_, x0seq_bf);
  if (tier1)
    conv_w<<<16000, 256, 0, stream>>>(dec_W, H_, 0, nullptr, 0, V_, decW_bf);

  // y_w, xg0
  gemm_bt<<<32, 256, 0, stream>>>(x0w_bf, B_, wih0a_bf, bias0p,
                                  nullptr, 0, -1, y_w, G_, G_, 32, 1, 0);
  gemm_bt<<<800, 256, 0, stream>>>(x0seq_bf, T_ * B_, wih0b_bf, nullptr,
                                   y_w, G_, 63, xg0, G_, G_, 32, 25, 0);

  // ---- layer 0: flag-synced persistent recurrence ----
  rnn_pers2<false><<<64, 256, 0, stream>>>(
      whh0_bf, xg0, cL0, hL0, hs0slots, nullptr, flg0, T_);

  // xg1 = hs0 @ Wih1^T + bias1p  (slots 1..50 are timesteps 0..49)
  gemm_bt<<<800, 256, 0, stream>>>(hs0slots + B_ * 2048, T_ * B_, wih1_bf, bias1p,
                                   nullptr, 0, -1, xg1, G_, G_, 32, 25, 0);

  if (tier1) {
    rnn_pers2<false><<<64, 256, 0, stream>>>(
        whh1_bf, xg1, cL1, hL1, hs1slots, nullptr, flg1, T_);
    gemm_bt<<<6250, 256, 0, stream>>>(hs1slots + B_ * 2048, T_ * B_, decW_bf, dec_b,
                                      nullptr, 0, -1, out, V_, V_, 250, 25, 1);
  } else if (tier2) {
    rnn_pers2<true><<<64, 256, 0, stream>>>(
        whh1_bf, xg1, cL1, hL1, hs0slots, hs1f, flg1, T_);
    gemm_sp<false, false><<<6250, 256, 0, stream>>>(
        hs1f, nullptr, H_, dec_W, H_, 0, dec_b, nullptr, 0, -1,
        out, V_, T_ * B_, V_, H_, 250);
  } else {
    for (int t = 0; t < T_; ++t) {
      const u16* hp = t ? ((t & 1) ? hbfA : hbfB) : hs0slots;
      u16* ho = (t & 1) ? hbfB : hbfA;
      rnn_step<false><<<64, 256, 0, stream>>>(
          hp, whh1_bf, xg1 + (size_t)t * B_ * G_, cL1, hL1, ho, nullptr);
      gemm_sp<false, false><<<250, 256, 0, stream>>>(
          hL1, nullptr, H_, dec_W, H_, 0, dec_b, nullptr, 0, -1,
          out + (size_t)t * B_ * V_, V_, B_, V_, H_, 250);
    }
  }
}